// Round 6
// baseline (318.125 us; speedup 1.0000x reference)
//
#include <hip/hip_runtime.h>

// LSTM B=2048, T=512, I=1, H=64, O=1 (PyTorch gate order i,f,g,o).
// v6 = round-4 parallelism + round-5 register-gate j-partition:
//   WG = 256 thr (4 waves) owns NBW=4 batches; grid = 512 (2 WG/CU, 2 waves/SIMD).
//   Wave wv computes ALL 4 gate types for j in [16wv,16wv+16): G^T = W @ h^T,
//   A = W frags (VGPRs), B = h (LDS fp16, XOR-swizzled, double-buffered).
//   After 8 MFMAs the 16 holder lanes (col=batch<4) hold all gates in regs;
//   an INTRA-WAVE LDS transpose (cg buffer, no barrier, conflict-free XOR
//   layout) spreads them so all 64 lanes do 1 state each (optimal trans-op
//   spread: 10 trans/wave-step). ONE barrier/step (cross-wave h exchange).
// Gate pre-scaling: W,b,w_ih scaled by -log2e (i,f,o) / -2log2e (g) so
//   sigmoid/tanh = rcp(1+exp2(g)), no pre-multiply, saturating.

typedef float    f32x4 __attribute__((ext_vector_type(4)));
typedef _Float16 f16x8 __attribute__((ext_vector_type(8)));

namespace {
constexpr int Bsz = 2048;
constexpr int Tsz = 512;
constexpr int NBW = 4;    // batches per workgroup
}

__device__ __forceinline__ float rcp_f(float v)  { return __builtin_amdgcn_rcpf(v); }
__device__ __forceinline__ float exp2_f(float v) { return __builtin_amdgcn_exp2f(v); }

// gs = -log2e * gate -> sigmoid(gate); saturates at +-inf
__device__ __forceinline__ float sigm_s(float gs) {
    return rcp_f(1.0f + exp2_f(gs));
}
// gs = -2log2e * gate -> tanh(gate)
__device__ __forceinline__ float tanh_s(float gs) {
    return fmaf(2.0f, rcp_f(1.0f + exp2_f(gs)), -1.0f);
}
// plain tanh for cell state
__device__ __forceinline__ float tanh_plain(float v) {
    return fmaf(2.0f, rcp_f(1.0f + exp2_f(v * -2.88539008178f)), -1.0f);
}

__global__ __launch_bounds__(256, 2)
void lstm_v6(const float* __restrict__ x,      // [B,T]
             const float* __restrict__ w_ih,   // [256]
             const float* __restrict__ w_hh,   // [256,64]
             const float* __restrict__ b_ih,   // [256]
             const float* __restrict__ b_hh,   // [256]
             const float* __restrict__ w_lin,  // [64]
             const float* __restrict__ b_lin,  // [1]
             float* __restrict__ out)          // [B]
{
    // h in MFMA-B layout: 16 rows (n=batch; rows 4..15 stay zero) x 128 B of
    // fp16 k-values, byte ^= (row&7)<<4, double-buffered.
    __shared__ __align__(16) char hAb[2][16 * 128];   // 4 KB
    // per-wave gate-transpose buffer: [b(4)][jl(16)][g(4)] f32,
    // byte-in-row = (jl*16 ^ (b<<4)) + g*4  -> conflict-free both sides
    __shared__ __align__(16) char cg[4][1024];        // 4 KB
    __shared__ float part[16];

    const int tid = threadIdx.x;
    const int wv  = tid >> 6;
    const int ln  = tid & 63;
    const int row = ln & 15;     // MFMA col index (batch; valid < 4)
    const int grp = ln >> 4;
    const int b0  = blockIdx.x * NBW;

    constexpr float LOG2E = 1.44269504089f;

    // ---- A-operand W fragments (one-time), pre-scaled per gate type ----
    // tile g covers gates [g*64 + 16wv, +16). A-frag: m = row, k = kc*32+grp*8+e
    f16x8 Wf[4][2];
    float wihc[4][4], biasc[4][4];
    #pragma unroll
    for (int g = 0; g < 4; ++g) {
        const float s = (g == 2) ? (-2.0f * LOG2E) : (-LOG2E);
        const float* wrow = w_hh + (size_t)(g * 64 + 16 * wv + row) * 64;
        #pragma unroll
        for (int kc = 0; kc < 2; ++kc) {
            const float4 a = ((const float4*)wrow)[kc * 8 + grp * 2 + 0];
            const float4 b = ((const float4*)wrow)[kc * 8 + grp * 2 + 1];
            f16x8 w;
            w[0] = (_Float16)(a.x * s); w[1] = (_Float16)(a.y * s);
            w[2] = (_Float16)(a.z * s); w[3] = (_Float16)(a.w * s);
            w[4] = (_Float16)(b.x * s); w[5] = (_Float16)(b.y * s);
            w[6] = (_Float16)(b.z * s); w[7] = (_Float16)(b.w * s);
            Wf[g][kc] = w;
        }
        #pragma unroll
        for (int reg = 0; reg < 4; ++reg) {
            const int gt = g * 64 + 16 * wv + 4 * grp + reg;
            wihc[g][reg]  = w_ih[gt] * s;
            biasc[g][reg] = (b_ih[gt] + b_hh[gt]) * s;
        }
    }

    // ---- B-frag read offsets ----
    const int sw    = (row & 7) << 4;
    const int boff0 = row * 128 + ((0 * 64 + grp * 16) ^ sw);
    const int boff1 = row * 128 + ((1 * 64 + grp * 16) ^ sw);

    // ---- cg offsets ----
    // write (holder lane, row<4): per reg, 16B at wv*1024 + row*256 + ((4grp+reg)*16 ^ row<<4)
    int cwoff[4];
    #pragma unroll
    for (int reg = 0; reg < 4; ++reg)
        cwoff[reg] = wv * 1024 + row * 256 + ((((grp << 2) + reg) * 16) ^ (row << 4));
    // read (all lanes): state (pb = ln&3, jl = ln>>2)
    const int pb  = ln & 3;
    const int jl  = ln >> 2;
    const int croff = wv * 1024 + pb * 256 + ((jl * 16) ^ (pb << 4));
    // h write: j = 16wv + jl, B-layout row pb
    const int j_own = 16 * wv + jl;
    const int hwoff = pb * 128 + ((2 * j_own) ^ (pb << 4));
    const float wlin = w_lin[j_own];

    // zero both h buffers (rows 4..15 must be 0; rows 0..3 = h0 = 0)
    ((float4*)hAb)[tid] = make_float4(0.f, 0.f, 0.f, 0.f);   // 256*16B = 4KB

    // per-lane x stream (batch = ln&3; cols 4..15 junk-but-unused)
    const float4* xp4 = (const float4*)(x + (size_t)(b0 + (ln & 3)) * Tsz);
    float4 xcur = xp4[0];

    float c = 0.0f, h = 0.0f;

    __syncthreads();

    for (int t4 = 0; t4 < Tsz / 4; ++t4) {
        const float4 xnxt = xp4[(t4 < Tsz / 4 - 1) ? (t4 + 1) : (Tsz / 4 - 1)];

        #pragma unroll
        for (int s = 0; s < 4; ++s) {
            const int rp = s & 1;          // t = 4*t4+s; read parity = t&1
            const int wp = rp ^ 1;
            const float xs = (s == 0) ? xcur.x : (s == 1) ? xcur.y
                           : (s == 2) ? xcur.z : xcur.w;

            const f16x8 B0 = *(const f16x8*)(hAb[rp] + boff0);
            const f16x8 B1 = *(const f16x8*)(hAb[rp] + boff1);

            f32x4 acc[4];
            #pragma unroll
            for (int g = 0; g < 4; ++g) {
                #pragma unroll
                for (int reg = 0; reg < 4; ++reg)
                    acc[g][reg] = fmaf(xs, wihc[g][reg], biasc[g][reg]);
            }
            #pragma unroll
            for (int g = 0; g < 4; ++g)
                acc[g] = __builtin_amdgcn_mfma_f32_16x16x32_f16(Wf[g][0], B0, acc[g], 0, 0, 0);
            #pragma unroll
            for (int g = 0; g < 4; ++g)
                acc[g] = __builtin_amdgcn_mfma_f32_16x16x32_f16(Wf[g][1], B1, acc[g], 0, 0, 0);

            // ---- intra-wave gate transpose: holders (row<4) write float4
            //      (i,f,g,o per jl), then every lane reads its own state ----
            if (row < 4) {
                #pragma unroll
                for (int reg = 0; reg < 4; ++reg) {
                    f32x4 cw;
                    cw[0] = acc[0][reg]; cw[1] = acc[1][reg];
                    cw[2] = acc[2][reg]; cw[3] = acc[3][reg];
                    *(f32x4*)(cg[0] + cwoff[reg]) = cw;
                }
            }
            // same-wave RAW on LDS: wait writes, then read (no barrier)
            asm volatile("s_waitcnt lgkmcnt(0)" ::: "memory");
            const f32x4 g4 = *(const f32x4*)(cg[0] + croff);

            // ---- activations: 1 state/lane, all 64 lanes ----
            const float ig = sigm_s(g4[0]);
            const float fg = sigm_s(g4[1]);
            const float tg = tanh_s(g4[2]);
            const float og = sigm_s(g4[3]);
            c = fmaf(fg, c, ig * tg);
            h = og * tanh_plain(c);

            *(_Float16*)(hAb[wp] + hwoff) = (_Float16)h;

            __syncthreads();               // the ONLY barrier per step
        }
        xcur = xnxt;
    }

    // ---- out[b0+b] = sum_j h[b][j]*w_lin[j] + b_lin ----
    // lane = jl*4 + pb: reduce over jl bits (offsets 4..32)
    float p = h * wlin;
    #pragma unroll
    for (int off = 4; off < 64; off <<= 1)
        p += __shfl_xor(p, off, 64);
    if (ln < 4) part[wv * 4 + ln] = p;     // lane ln holds batch ln's wave-sum
    __syncthreads();
    if (tid < 4)
        out[b0 + tid] = part[tid] + part[4 + tid] +
                        part[8 + tid] + part[12 + tid] + b_lin[0];
}

extern "C" void kernel_launch(void* const* d_in, const int* in_sizes, int n_in,
                              void* d_out, int out_size, void* d_ws, size_t ws_size,
                              hipStream_t stream) {
    const float* x     = (const float*)d_in[0];
    const float* w_ih  = (const float*)d_in[1];
    const float* w_hh  = (const float*)d_in[2];
    const float* b_ih  = (const float*)d_in[3];
    const float* b_hh  = (const float*)d_in[4];
    const float* w_lin = (const float*)d_in[5];
    const float* b_lin = (const float*)d_in[6];
    float* out = (float*)d_out;

    dim3 grid(Bsz / NBW);   // 512
    dim3 block(256);
    lstm_v6<<<grid, block, 0, stream>>>(x, w_ih, w_hh, b_ih, b_hh,
                                        w_lin, b_lin, out);
}